// Round 3
// baseline (224.638 us; speedup 1.0000x reference)
//
#include <hip/hip_runtime.h>
#include <math.h>

#define SRC 448
#define OUTN 224
#define BPI 196                 // blocks per image: 224*224/256
#define NWG (BPI * 64)          // 12544 total blocks, divisible by 8
#define CPX (NWG / 8)           // 1568 blocks per XCD chunk

__device__ __forceinline__ float sig10(float z) {
    return 1.0f / (1.0f + __expf(-10.0f * z));
}

__global__ __launch_bounds__(256) void attn_crop_kernel(
    const float* __restrict__ img,   // [B,3,448,448]
    const float* __restrict__ locs,  // [B,3]
    float* __restrict__ out)         // [B,3,224,224]
{
    // XCD-aware bijective swizzle: each XCD gets a contiguous chunk of blocks
    // (~8 whole images) so adjacent output rows hit the same L2.
    const int bid = blockIdx.x;
    const int swz = (bid & 7) * CPX + (bid >> 3);
    const int b = swz / BPI;
    const int pix = (swz - b * BPI) * 256 + threadIdx.x;   // < 50176 always
    const int jr = pix / OUTN;
    const int jc = pix - jr * OUTN;

    const float Sf = (float)SRC;
    float tx = locs[b * 3 + 0];
    float ty = locs[b * 3 + 1];
    float tl = locs[b * 3 + 2];
    // exact reference clamp order (jnp.clip = min(max(x,lo),hi))
    tl = fminf(fmaxf(tl, Sf / 3.0f), Sf * 2.0f / 3.0f);
    tx = fminf(fmaxf(tx, tl), Sf - tl);
    ty = fminf(fmaxf(ty, tl), Sf - tl);
    const float w_off = fmaxf(floorf(tx - tl), 0.0f);
    const float h_off = fmaxf(floorf(ty - tl), 0.0f);
    const float w_end = fminf(floorf(tx + tl), Sf);
    const float h_end = fminf(floorf(ty + tl), Sf);
    const float Lw = w_end - w_off;
    const float Lh = h_end - h_off;

    const float inv = 1.0f / (float)(OUTN - 1);
    const float r = w_off + ((float)jr * inv) * (Lw - 1.0f);
    const float c = h_off + ((float)jc * inv) * (Lh - 1.0f);
    const float r0 = fminf(fmaxf(floorf(r), 0.0f), Sf - 1.0f);
    const float c0 = fminf(fmaxf(floorf(c), 0.0f), Sf - 1.0f);
    const float wr = r - r0;
    const float wc = c - c0;
    const int r0i = (int)r0;
    const int c0i = (int)c0;
    const int r1i = min(r0i + 1, SRC - 1);
    const int c1i = min(c0i + 1, SRC - 1);

    // soft-mask values folded into the 4 bilinear weights
    const float mx0 = sig10((float)r0i - w_off) - sig10((float)r0i - w_end);
    const float mx1 = sig10((float)r1i - w_off) - sig10((float)r1i - w_end);
    const float my0 = sig10((float)c0i - h_off) - sig10((float)c0i - h_end);
    const float my1 = sig10((float)c1i - h_off) - sig10((float)c1i - h_end);

    const float w00 = (1.0f - wr) * (1.0f - wc) * mx0 * my0;
    const float w01 = (1.0f - wr) * wc          * mx0 * my1;
    const float w10 = wr          * (1.0f - wc) * mx1 * my0;
    const float w11 = wr          * wc          * mx1 * my1;

    const float* base = img + (size_t)b * 3 * SRC * SRC;
    float* ob = out + (size_t)b * 3 * OUTN * OUTN + (size_t)jr * OUTN + jc;

#pragma unroll
    for (int ch = 0; ch < 3; ++ch) {
        const float* p = base + (size_t)ch * SRC * SRC;
        const float* pr0 = p + (size_t)r0i * SRC;
        const float* pr1 = p + (size_t)r1i * SRC;
        const float v00 = pr0[c0i];
        const float v01 = pr0[c1i];
        const float v10 = pr1[c0i];
        const float v11 = pr1[c1i];
        const float res = v00 * w00 + v01 * w01 + v10 * w10 + v11 * w11;
        __builtin_nontemporal_store(res, ob + (size_t)ch * OUTN * OUTN);
    }
}

extern "C" void kernel_launch(void* const* d_in, const int* in_sizes, int n_in,
                              void* d_out, int out_size, void* d_ws, size_t ws_size,
                              hipStream_t stream) {
    const float* img  = (const float*)d_in[0];
    const float* locs = (const float*)d_in[1];
    float* out = (float*)d_out;

    dim3 block(256);
    dim3 grid(NWG);   // 64 images * 196 blocks, flattened for XCD swizzle
    attn_crop_kernel<<<grid, block, 0, stream>>>(img, locs, out);
}

// Round 4
// 217.855 us; speedup vs baseline: 1.0311x; 1.0311x over previous
//
#include <hip/hip_runtime.h>
#include <math.h>

#define SRC 448
#define OUTN 224

__device__ __forceinline__ float sig10(float z) {
    // sigmoid(10*z); IEEE inf handling gives exact 0/1 saturation
    return 1.0f / (1.0f + __expf(-10.0f * z));
}

__global__ __launch_bounds__(256) void attn_crop_kernel(
    const float* __restrict__ img,   // [B,3,448,448]
    const float* __restrict__ locs,  // [B,3]
    float* __restrict__ out)         // [B,3,224,224]
{
    const int b = blockIdx.y;
    const int pix = blockIdx.x * 256 + threadIdx.x;
    if (pix >= OUTN * OUTN) return;
    const int jr = pix / OUTN;
    const int jc = pix - jr * OUTN;

    const float Sf = (float)SRC;
    float tx = locs[b * 3 + 0];
    float ty = locs[b * 3 + 1];
    float tl = locs[b * 3 + 2];
    // exact reference clamp order
    tl = fminf(fmaxf(tl, Sf / 3.0f), Sf * 2.0f / 3.0f);
    tx = fminf(fmaxf(tx, tl), Sf - tl);
    ty = fminf(fmaxf(ty, tl), Sf - tl);
    const float w_off = fmaxf(floorf(tx - tl), 0.0f);
    const float h_off = fmaxf(floorf(ty - tl), 0.0f);
    const float w_end = fminf(floorf(tx + tl), Sf);
    const float h_end = fminf(floorf(ty + tl), Sf);
    const float Lw = w_end - w_off;
    const float Lh = h_end - h_off;

    const float inv = 1.0f / (float)(OUTN - 1);
    const float r = w_off + ((float)jr * inv) * (Lw - 1.0f);
    const float c = h_off + ((float)jc * inv) * (Lh - 1.0f);
    const float r0 = fminf(fmaxf(floorf(r), 0.0f), Sf - 1.0f);
    const float c0 = fminf(fmaxf(floorf(c), 0.0f), Sf - 1.0f);
    const float wr = r - r0;
    const float wc = c - c0;
    const int r0i = (int)r0;
    const int c0i = (int)c0;
    const int r1i = min(r0i + 1, SRC - 1);
    const int c1i = min(c0i + 1, SRC - 1);

    // soft-mask values at the 4 tap rows/cols (folded into weights)
    const float mx0 = sig10((float)r0i - w_off) - sig10((float)r0i - w_end);
    const float mx1 = sig10((float)r1i - w_off) - sig10((float)r1i - w_end);
    const float my0 = sig10((float)c0i - h_off) - sig10((float)c0i - h_end);
    const float my1 = sig10((float)c1i - h_off) - sig10((float)c1i - h_end);

    const float w00 = (1.0f - wr) * (1.0f - wc) * mx0 * my0;
    const float w01 = (1.0f - wr) * wc          * mx0 * my1;
    const float w10 = wr          * (1.0f - wc) * mx1 * my0;
    const float w11 = wr          * wc          * mx1 * my1;

    const float* base = img + (size_t)b * 3 * SRC * SRC;
    float* ob = out + (size_t)b * 3 * OUTN * OUTN + (size_t)jr * OUTN + jc;

#pragma unroll
    for (int ch = 0; ch < 3; ++ch) {
        const float* p = base + (size_t)ch * SRC * SRC;
        const float v00 = p[r0i * SRC + c0i];
        const float v01 = p[r0i * SRC + c1i];
        const float v10 = p[r1i * SRC + c0i];
        const float v11 = p[r1i * SRC + c1i];
        ob[(size_t)ch * OUTN * OUTN] = v00 * w00 + v01 * w01 + v10 * w10 + v11 * w11;
    }
}

extern "C" void kernel_launch(void* const* d_in, const int* in_sizes, int n_in,
                              void* d_out, int out_size, void* d_ws, size_t ws_size,
                              hipStream_t stream) {
    const float* img  = (const float*)d_in[0];
    const float* locs = (const float*)d_in[1];
    float* out = (float*)d_out;

    const int B = in_sizes[1] / 3;  // 64
    dim3 block(256);
    dim3 grid((OUTN * OUTN + 255) / 256, B);
    attn_crop_kernel<<<grid, block, 0, stream>>>(img, locs, out);
}